// Round 14
// baseline (54.620 us; speedup 1.0000x reference)
//
#include <hip/hip_runtime.h>
#include <hip/hip_bf16.h>
#include <stdint.h>

// Quanvolution + linear(784->10) + log_softmax via MFMA, B=65536, fp32 in/out.
// R13 = R12 with the nontemporal-builtin type fixed (ext_vector float4, not
// HIP_vector_type). Theory: x granules are single-touch -> L1 allocation is
// pure pollution that evicts the block's W-fragments (25KB) between preload
// and use. `nt` x-loads keep W L1-resident and skip allocate/evict in TCP.
//  - 4096 blocks x 256 thr; block = 16 rows; wave kq = K-quarter (7/6/6/6).
//  - per wave ONE hoisted load window (all x-float4s + W-frags up front).
//  - merge via 3KB LDS, 1 barrier; kq0 does the shuffle log_softmax epilogue.
// K-slot map (validated R9/R10): K-block kt covers row bytes [128kt,128kt+128);
// lane (r16,kg) loads float4 at +16kg and +64+16kg; every even float pair is
// a top/bottom pair of one patch; pads (jp>=784) have W=0; kt=24 second quad
// clamps to row start (W=0 annihilates).

typedef __attribute__((ext_vector_type(8))) short short8;
typedef __attribute__((ext_vector_type(4))) float f32x4;

// ---- pre-kernel: bake W -> bf16 frags ws[kt][lane][e], 25 KB ----
__global__ void quanv_wprep_kernel(const float* __restrict__ Wm,
                                   uint32_t* __restrict__ ws) {
    const int idx = blockIdx.x * 256 + threadIdx.x;   // [0, 6400)
    if (idx >= 6400) return;
    const int kt  = idx >> 8;       // 0..24
    const int rem = idx & 255;
    const int l   = rem >> 2;       // lane 0..63
    const int d   = rem & 3;        // u32 -> e = 2d, 2d+1
    const int n   = l & 15;
    const int kg  = l >> 4;
    uint32_t outv = 0;
    if (n < 10) {
        uint32_t hv[2];
#pragma unroll
        for (int d2 = 0; d2 < 2; ++d2) {
            const int e  = 2 * d + d2;
            const int jp = 32 * kt + 4 * kg + 16 * (e >> 2) + 2 * ((e >> 1) & 1);
            float v = 0.f;
            if (jp < 784) {
                const int ri = jp / 28;          // image row
                const int pc = (jp % 28) >> 1;   // patch col
                const int pr = ri >> 1;          // patch row
                const int ho = ri & 1;           // 0=top pair, 1=bottom pair
                const int col = (pr * 14 + pc) * 4 + 2 * ho + (e & 1);
                v = Wm[n * 784 + col];
            }
            hv[d2] = (uint32_t)__bfloat16_as_ushort(__float2bfloat16(v));
        }
        outv = hv[0] | (hv[1] << 16);
    }
    ws[idx] = outv;
}

// ---- 8 features from two f32x4s (pairs (0,1),(2,3) each) ----
#define FEAT8(VA, VB, A) do {                                                 \
    { const float ce=__cosf((VA)[0]), co=__cosf((VA)[1]);                     \
      (A)[0]=(short)__bfloat16_as_ushort(__float2bfloat16(ce + (VA)[0]));     \
      (A)[1]=(short)__bfloat16_as_ushort(__float2bfloat16(fmaf(ce,co,(VA)[1])));}\
    { const float ce=__cosf((VA)[2]), co=__cosf((VA)[3]);                     \
      (A)[2]=(short)__bfloat16_as_ushort(__float2bfloat16(ce + (VA)[2]));     \
      (A)[3]=(short)__bfloat16_as_ushort(__float2bfloat16(fmaf(ce,co,(VA)[3])));}\
    { const float ce=__cosf((VB)[0]), co=__cosf((VB)[1]);                     \
      (A)[4]=(short)__bfloat16_as_ushort(__float2bfloat16(ce + (VB)[0]));     \
      (A)[5]=(short)__bfloat16_as_ushort(__float2bfloat16(fmaf(ce,co,(VB)[1])));}\
    { const float ce=__cosf((VB)[2]), co=__cosf((VB)[3]);                     \
      (A)[6]=(short)__bfloat16_as_ushort(__float2bfloat16(ce + (VB)[2]));     \
      (A)[7]=(short)__bfloat16_as_ushort(__float2bfloat16(fmaf(ce,co,(VB)[3])));}\
} while (0)

// ---- one K-window: issue ALL loads (x non-temporal), then compute ----
template <int KT0, int N>
__device__ __forceinline__ void quarter(const float* __restrict__ px,
                                        const char* __restrict__ wsb,
                                        int l, f32x4& acc) {
    f32x4 va[N], vb[N];
    short8 wf[N];
    const char* wbp = wsb + KT0 * 1024 + l * 16;
#pragma unroll
    for (int j = 0; j < N; ++j) {
        const int kt = KT0 + j;
        va[j] = __builtin_nontemporal_load((const f32x4*)(px + 32 * kt));
        // kt=24 second quad would cross the row end -> clamp (W=0 kills it)
        vb[j] = (kt == 24)
                  ? __builtin_nontemporal_load((const f32x4*)(px))
                  : __builtin_nontemporal_load((const f32x4*)(px + 32 * kt + 16));
        wf[j] = *(const short8*)(wbp + j * 1024);   // cached: reused per block
    }
#pragma unroll
    for (int j = 0; j < N; ++j) {
        short8 a;
        FEAT8(va[j], vb[j], a);
        acc = __builtin_amdgcn_mfma_f32_16x16x32_bf16(a, wf[j], acc, 0, 0, 0);
    }
}

__global__ __launch_bounds__(256, 4)
void quanv_mfma8_kernel(const float* __restrict__ x,
                        const char* __restrict__ wsb,   // bf16 frags [25][64][8]
                        const float* __restrict__ bias,
                        float* __restrict__ out) {
    __shared__ f32x4 red[3][64];   // 3 KB: kq=1..3 accumulators

    const int t   = threadIdx.x;
    const int l   = t & 63;
    const int kq  = __builtin_amdgcn_readfirstlane(t >> 6);   // K-quarter 0..3
    const int r16 = l & 15;
    const int kg  = l >> 4;
    const int rowBase = blockIdx.x * 16;
    const float* px = x + (size_t)(rowBase + r16) * 784 + 4 * kg;

    f32x4 acc = {0.f, 0.f, 0.f, 0.f};

    if      (kq == 0) quarter<0, 7>(px, wsb, l, acc);
    else if (kq == 1) quarter<7, 6>(px, wsb, l, acc);
    else if (kq == 2) quarter<13, 6>(px, wsb, l, acc);
    else              quarter<19, 6>(px, wsb, l, acc);

    // ---- merge K-quarters via LDS ----
    if (kq != 0) red[kq - 1][l] = acc;
    __syncthreads();
    if (kq == 0) {
#pragma unroll
        for (int s = 0; s < 3; ++s) {
            const f32x4 o = red[s][l];
#pragma unroll
            for (int j = 0; j < 4; ++j) acc[j] += o[j];
        }

        // ---- epilogue: lane holds D[m=4*kg+j][n=r16]; log_softmax over n ----
        const float bn = bias[r16 < 10 ? r16 : 0];
#pragma unroll
        for (int j = 0; j < 4; ++j) {
            float v = (r16 < 10) ? (acc[j] + bn) : -1e30f;
            float mx = v;
            mx = fmaxf(mx, __shfl_xor(mx, 1, 64));
            mx = fmaxf(mx, __shfl_xor(mx, 2, 64));
            mx = fmaxf(mx, __shfl_xor(mx, 4, 64));
            mx = fmaxf(mx, __shfl_xor(mx, 8, 64));
            float e = (r16 < 10) ? __expf(v - mx) : 0.f;
            float s = e;
            s += __shfl_xor(s, 1, 64);
            s += __shfl_xor(s, 2, 64);
            s += __shfl_xor(s, 4, 64);
            s += __shfl_xor(s, 8, 64);
            const float ls = __logf(s) + mx;
            if (r16 < 10)
                out[(size_t)(rowBase + 4 * kg + j) * 10 + r16] = v - ls;
        }
    }
}

extern "C" void kernel_launch(void* const* d_in, const int* in_sizes, int n_in,
                              void* d_out, int out_size, void* d_ws, size_t ws_size,
                              hipStream_t stream) {
    const float* x    = (const float*)d_in[0];   // [65536, 784]
    const float* Wm   = (const float*)d_in[1];   // [10, 784]
    const float* bias = (const float*)d_in[2];   // [10]
    float* out        = (float*)d_out;           // [65536, 10]

    quanv_wprep_kernel<<<dim3(25), dim3(256), 0, stream>>>(
        Wm, (uint32_t*)d_ws);
    quanv_mfma8_kernel<<<dim3(4096), dim3(256), 0, stream>>>(
        x, (const char*)d_ws, bias, out);
}

// Round 15
// 39.100 us; speedup vs baseline: 1.3969x; 1.3969x over previous
//
#include <hip/hip_runtime.h>
#include <hip/hip_bf16.h>
#include <stdint.h>

// Quanvolution + linear(784->10) + log_softmax via MFMA, B=65536, fp32 in/out.
// R14: R10's validated structure (40.0us) + serial-tail-free epilogue.
// nt loads reverted (R13: -36%, L3 residency of x matters).
// NEW epilogue: all 4 waves write acc to LDS [kq][row16][n] (4KB); barrier;
// lanes 0-15 of wave0 each own ONE ROW: merge 4 partials + bias, 10-wide
// in-register log_softmax (NO shuffles - the old 8-deep ds-pipe chain was
// ~2000 serial cycles/block), coalesced 40B row store (5 x float2).
//  - 4096 blocks x 256 thr; block = 16 rows; wave kq = K-quarter (7/6/6/6).
//  - per wave ONE hoisted load window (all x-float4s + W-frags up front).
// K-slot map (validated R9/R10): K-block kt covers row bytes [128kt,128kt+128);
// lane (r16,kg) loads float4 at +16kg and +64+16kg; every even float pair is
// a top/bottom pair of one patch; pads (jp>=784) have W=0; kt=24 second quad
// clamps to row start (W=0 annihilates).

typedef __attribute__((ext_vector_type(8))) short short8;
typedef __attribute__((ext_vector_type(4))) float f32x4;

// ---- pre-kernel: bake W -> bf16 frags ws[kt][lane][e], 25 KB ----
__global__ void quanv_wprep_kernel(const float* __restrict__ Wm,
                                   uint32_t* __restrict__ ws) {
    const int idx = blockIdx.x * 256 + threadIdx.x;   // [0, 6400)
    if (idx >= 6400) return;
    const int kt  = idx >> 8;       // 0..24
    const int rem = idx & 255;
    const int l   = rem >> 2;       // lane 0..63
    const int d   = rem & 3;        // u32 -> e = 2d, 2d+1
    const int n   = l & 15;
    const int kg  = l >> 4;
    uint32_t outv = 0;
    if (n < 10) {
        uint32_t hv[2];
#pragma unroll
        for (int d2 = 0; d2 < 2; ++d2) {
            const int e  = 2 * d + d2;
            const int jp = 32 * kt + 4 * kg + 16 * (e >> 2) + 2 * ((e >> 1) & 1);
            float v = 0.f;
            if (jp < 784) {
                const int ri = jp / 28;          // image row
                const int pc = (jp % 28) >> 1;   // patch col
                const int pr = ri >> 1;          // patch row
                const int ho = ri & 1;           // 0=top pair, 1=bottom pair
                const int col = (pr * 14 + pc) * 4 + 2 * ho + (e & 1);
                v = Wm[n * 784 + col];
            }
            hv[d2] = (uint32_t)__bfloat16_as_ushort(__float2bfloat16(v));
        }
        outv = hv[0] | (hv[1] << 16);
    }
    ws[idx] = outv;
}

// ---- 8 features from two f32x4s (pairs (0,1),(2,3) each) ----
#define FEAT8(VA, VB, A) do {                                                 \
    { const float ce=__cosf((VA)[0]), co=__cosf((VA)[1]);                     \
      (A)[0]=(short)__bfloat16_as_ushort(__float2bfloat16(ce + (VA)[0]));     \
      (A)[1]=(short)__bfloat16_as_ushort(__float2bfloat16(fmaf(ce,co,(VA)[1])));}\
    { const float ce=__cosf((VA)[2]), co=__cosf((VA)[3]);                     \
      (A)[2]=(short)__bfloat16_as_ushort(__float2bfloat16(ce + (VA)[2]));     \
      (A)[3]=(short)__bfloat16_as_ushort(__float2bfloat16(fmaf(ce,co,(VA)[3])));}\
    { const float ce=__cosf((VB)[0]), co=__cosf((VB)[1]);                     \
      (A)[4]=(short)__bfloat16_as_ushort(__float2bfloat16(ce + (VB)[0]));     \
      (A)[5]=(short)__bfloat16_as_ushort(__float2bfloat16(fmaf(ce,co,(VB)[1])));}\
    { const float ce=__cosf((VB)[2]), co=__cosf((VB)[3]);                     \
      (A)[6]=(short)__bfloat16_as_ushort(__float2bfloat16(ce + (VB)[2]));     \
      (A)[7]=(short)__bfloat16_as_ushort(__float2bfloat16(fmaf(ce,co,(VB)[3])));}\
} while (0)

// ---- one K-window: issue ALL loads, then compute (full static unroll) ----
template <int KT0, int N>
__device__ __forceinline__ void quarter(const float* __restrict__ px,
                                        const char* __restrict__ wsb,
                                        int l, f32x4& acc) {
    f32x4 va[N], vb[N];
    short8 wf[N];
    const char* wbp = wsb + KT0 * 1024 + l * 16;
#pragma unroll
    for (int j = 0; j < N; ++j) {
        const int kt = KT0 + j;
        va[j] = *(const f32x4*)(px + 32 * kt);
        // kt=24 second quad would cross the row end -> clamp (W=0 kills it)
        vb[j] = (kt == 24) ? *(const f32x4*)(px)
                           : *(const f32x4*)(px + 32 * kt + 16);
        wf[j] = *(const short8*)(wbp + j * 1024);
    }
#pragma unroll
    for (int j = 0; j < N; ++j) {
        short8 a;
        FEAT8(va[j], vb[j], a);
        acc = __builtin_amdgcn_mfma_f32_16x16x32_bf16(a, wf[j], acc, 0, 0, 0);
    }
}

__global__ __launch_bounds__(256, 4)
void quanv_mfma9_kernel(const float* __restrict__ x,
                        const char* __restrict__ wsb,   // bf16 frags [25][64][8]
                        const float* __restrict__ bias,
                        float* __restrict__ out) {
    __shared__ float red[4][16][16];   // 4 KB: [kq][row16][class]

    const int t   = threadIdx.x;
    const int l   = t & 63;
    const int kq  = __builtin_amdgcn_readfirstlane(t >> 6);   // K-quarter 0..3
    const int r16 = l & 15;
    const int kg  = l >> 4;
    const int rowBase = blockIdx.x * 16;
    const float* px = x + (size_t)(rowBase + r16) * 784 + 4 * kg;

    f32x4 acc = {0.f, 0.f, 0.f, 0.f};

    if      (kq == 0) quarter<0, 7>(px, wsb, l, acc);
    else if (kq == 1) quarter<7, 6>(px, wsb, l, acc);
    else if (kq == 2) quarter<13, 6>(px, wsb, l, acc);
    else              quarter<19, 6>(px, wsb, l, acc);

    // ---- all waves deposit partials: D[m=4*kg+j][n=r16] ----
#pragma unroll
    for (int j = 0; j < 4; ++j) red[kq][4 * kg + j][r16] = acc[j];
    __syncthreads();

    // ---- epilogue: lane r (first 16 threads) owns row r; no shuffles ----
    if (t < 16) {
        const int r = t;
        float lg[10];
#pragma unroll
        for (int n = 0; n < 10; ++n)
            lg[n] = red[0][r][n] + red[1][r][n] + red[2][r][n] + red[3][r][n]
                  + bias[n];

        float mx = lg[0];
#pragma unroll
        for (int n = 1; n < 10; ++n) mx = fmaxf(mx, lg[n]);
        float sum = 0.f;
#pragma unroll
        for (int n = 0; n < 10; ++n) sum += __expf(lg[n] - mx);
        const float ls = __logf(sum) + mx;

        float* o = out + (size_t)(rowBase + r) * 10;   // 40B row, coalesced
#pragma unroll
        for (int n = 0; n < 10; n += 2)
            *(float2*)(o + n) = make_float2(lg[n] - ls, lg[n + 1] - ls);
    }
}

extern "C" void kernel_launch(void* const* d_in, const int* in_sizes, int n_in,
                              void* d_out, int out_size, void* d_ws, size_t ws_size,
                              hipStream_t stream) {
    const float* x    = (const float*)d_in[0];   // [65536, 784]
    const float* Wm   = (const float*)d_in[1];   // [10, 784]
    const float* bias = (const float*)d_in[2];   // [10]
    float* out        = (float*)d_out;           // [65536, 10]

    quanv_wprep_kernel<<<dim3(25), dim3(256), 0, stream>>>(
        Wm, (uint32_t*)d_ws);
    quanv_mfma9_kernel<<<dim3(4096), dim3(256), 0, stream>>>(
        x, (const char*)d_ws, bias, out);
}